// Round 2
// baseline (1163.733 us; speedup 1.0000x reference)
//
#include <hip/hip_runtime.h>

// ---------------- types & helpers ----------------
typedef __attribute__((ext_vector_type(8))) short frag8;   // 8 x bf16 (4 VGPRs)
typedef __attribute__((ext_vector_type(4))) float facc4;   // 4 x f32 accum

#define MFMA16(a,b,c) __builtin_amdgcn_mfma_f32_16x16x32_bf16((a),(b),(c),0,0,0)

__device__ __forceinline__ unsigned short f2bf(float f){
  unsigned int u = __builtin_bit_cast(unsigned int, f);
  u += 0x7FFFu + ((u >> 16) & 1u);           // RNE
  return (unsigned short)(u >> 16);
}
__device__ __forceinline__ float bf2f(unsigned short h){
  unsigned int u = ((unsigned int)h) << 16;
  return __builtin_bit_cast(float, u);
}
__device__ __forceinline__ float gelu_f(float x){
  return 0.5f * x * (1.0f + erff(x * 0.70710678118654752440f));
}
__device__ __forceinline__ void gload16(const void* g, void* l){
  __builtin_amdgcn_global_load_lds(
      (const __attribute__((address_space(1))) void*)g,
      (__attribute__((address_space(3))) void*)l, 16, 0, 0);
}

// ---------------- fused f32->bf16 weight conversion (with row padding) ----------------
struct CvtSeg { const float* src; unsigned short* dst; long total; long blk_start; int rows_src; int K; };
struct CvtArgs { CvtSeg seg[12]; int nseg; };

__global__ void convert_all(CvtArgs a){
  long blk = blockIdx.x;
  int si = 0;
  for (int i = 1; i < a.nseg; i++) if (blk >= a.seg[i].blk_start) si = i;
  CvtSeg s = a.seg[si];
  long i = ((blk - s.blk_start) * 256 + threadIdx.x) * 4L;
  if (i >= s.total) return;
  long row = i / s.K;
  ushort4 o;
  if (row < s.rows_src){
    float4 v = *(const float4*)(s.src + i);
    o.x = f2bf(v.x); o.y = f2bf(v.y); o.z = f2bf(v.z); o.w = f2bf(v.w);
  } else { o.x = 0; o.y = 0; o.z = 0; o.w = 0; }
  *(ushort4*)(s.dst + i) = o;
}

// ---------------- positional encoding table ----------------
__global__ void pe_kernel(float* __restrict__ pe){
  const int s = blockIdx.x;
  const int t = threadIdx.x;
  float4 o;
#pragma unroll
  for (int e = 0; e < 4; e++){
    int c = t * 4 + e;
    int i2 = c & ~1;   // 2i
    float dv = expf(-0.0089944730195080f * (float)i2); // log(10000)/1024
    float ang = (float)s * dv;
    ((float*)&o)[e] = (c & 1) ? cosf(ang) : sinf(ang);
  }
  *(float4*)(pe + (size_t)s * 1024 + t * 4) = o;
}

// ---------------- GEMM: C[M,N] = A[M,K] * W[N,K]^T + bias ----------------
// EPI: 0 = f32 out, 1 = bf16 out, 2 = gelu -> bf16 out
template<int EPI>
__global__ __launch_bounds__(256, 2)
void gemm_bt(const unsigned short* __restrict__ A,
             const unsigned short* __restrict__ W,
             const float* __restrict__ bias,
             void* __restrict__ Cout,
             int K, int ldC, int coloff, int nvalid)
{
  __shared__ unsigned short As[128 * 32];
  __shared__ unsigned short Bs[128 * 32];
  const int tid = threadIdx.x;
  const int w = tid >> 6, lane = tid & 63;
  const int lh = lane & 15, lq = lane >> 4;
  const int wr = w >> 1, wc = w & 1;
  const long row0 = (long)blockIdx.x * 128;
  const long col0 = (long)blockIdx.y * 128;

  facc4 acc[4][4];
  const facc4 vz = {0.f, 0.f, 0.f, 0.f};
#pragma unroll
  for (int r = 0; r < 4; r++)
#pragma unroll
    for (int c = 0; c < 4; c++) acc[r][c] = vz;

  const int arow = w * 16 + (lane >> 2);
  const int aseg = (lane & 3) * 8;
  const unsigned short* A0 = A + (row0 + arow) * (long)K + aseg;
  const unsigned short* A1 = A + (row0 + 64 + arow) * (long)K + aseg;
  const unsigned short* W0 = W + (col0 + arow) * (long)K + aseg;
  const unsigned short* W1 = W + (col0 + 64 + arow) * (long)K + aseg;
  char* lA0 = (char*)As + w * 1024;
  char* lA1 = (char*)As + 4096 + w * 1024;
  char* lB0 = (char*)Bs + w * 1024;
  char* lB1 = (char*)Bs + 4096 + w * 1024;

  for (int k0 = 0; k0 < K; k0 += 32){
    gload16(A0 + k0, lA0);
    gload16(A1 + k0, lA1);
    gload16(W0 + k0, lB0);
    gload16(W1 + k0, lB1);
    __syncthreads();
    frag8 af[4], bf[4];
#pragma unroll
    for (int r = 0; r < 4; r++) af[r] = *(const frag8*)&As[(wr * 64 + r * 16 + lh) * 32 + lq * 8];
#pragma unroll
    for (int c = 0; c < 4; c++) bf[c] = *(const frag8*)&Bs[(wc * 64 + c * 16 + lh) * 32 + lq * 8];
#pragma unroll
    for (int r = 0; r < 4; r++)
#pragma unroll
      for (int c = 0; c < 4; c++)
        acc[r][c] = MFMA16(af[r], bf[c], acc[r][c]);
    __syncthreads();
  }

#pragma unroll
  for (int c = 0; c < 4; c++){
    const int colt = wc * 64 + c * 16 + lh;
    const long gcol = col0 + colt;
    const bool ok = gcol < nvalid;
    const float bv = ok ? bias[gcol] : 0.f;
#pragma unroll
    for (int r = 0; r < 4; r++){
#pragma unroll
      for (int j = 0; j < 4; j++){
        if (!ok) continue;
        const long grow = row0 + wr * 64 + r * 16 + lq * 4 + j;
        float v = acc[r][c][j] + bv;
        if (EPI == 2) v = gelu_f(v);
        const long off = grow * (long)ldC + coloff + gcol;
        if (EPI == 0) ((float*)Cout)[off] = v;
        else          ((unsigned short*)Cout)[off] = f2bf(v);
      }
    }
  }
}

// ---------------- LayerNorm (row=1024), residual in f32, bf16 copy out ----------------
// bmode: 0 = none, 1 = add bsrc[row], 2 = add bsrc[row & 1023]  (pos enc)
__global__ __launch_bounds__(256)
void ln_kernel(const float* __restrict__ a, const float* __restrict__ bsrc, int bmode,
               const float* __restrict__ g, const float* __restrict__ be,
               float* __restrict__ of32, unsigned short* __restrict__ obf)
{
  const int row = blockIdx.x;
  const int t = threadIdx.x;
  float4 x = ((const float4*)(a + (size_t)row * 1024))[t];
  if (bmode){
    const size_t brow = (bmode == 1) ? (size_t)row : (size_t)(row & 1023);
    float4 y = ((const float4*)(bsrc + brow * 1024))[t];
    x.x += y.x; x.y += y.y; x.z += y.z; x.w += y.w;
  }
  float s = x.x + x.y + x.z + x.w;
  float ss = x.x * x.x + x.y * x.y + x.z * x.z + x.w * x.w;
#pragma unroll
  for (int mk = 1; mk < 64; mk <<= 1){ s += __shfl_xor(s, mk); ss += __shfl_xor(ss, mk); }
  __shared__ float red[8];
  const int w = t >> 6, lane = t & 63;
  if (lane == 0){ red[w] = s; red[4 + w] = ss; }
  __syncthreads();
  s = red[0] + red[1] + red[2] + red[3];
  ss = red[4] + red[5] + red[6] + red[7];
  const float mean = s * (1.f / 1024.f);
  const float var = ss * (1.f / 1024.f) - mean * mean;
  const float rstd = rsqrtf(var + 1e-5f);
  float4 gg = ((const float4*)g)[t];
  float4 bb = ((const float4*)be)[t];
  float4 o;
  o.x = (x.x - mean) * rstd * gg.x + bb.x;
  o.y = (x.y - mean) * rstd * gg.y + bb.y;
  o.z = (x.z - mean) * rstd * gg.z + bb.z;
  o.w = (x.w - mean) * rstd * gg.w + bb.w;
  if (of32) ((float4*)(of32 + (size_t)row * 1024))[t] = o;
  if (obf){
    ushort4 hh;
    hh.x = f2bf(o.x); hh.y = f2bf(o.y); hh.z = f2bf(o.z); hh.w = f2bf(o.w);
    ((ushort4*)(obf + (size_t)row * 1024))[t] = hh;
  }
}

// ---------------- V transpose: vt[b][h][d][s] ----------------
__global__ void transpose_v(const unsigned short* __restrict__ qkv, unsigned short* __restrict__ vt){
  __shared__ unsigned short t[32][33];
  const int s0 = blockIdx.x * 32;
  const int d0 = blockIdx.y * 32;
  const int bh = blockIdx.z;
  const int b = bh >> 3, h = bh & 7;
  const int tx = threadIdx.x, ty = threadIdx.y;
#pragma unroll
  for (int j = 0; j < 4; j++){
    int srow = ty + j * 8;
    t[srow][tx] = qkv[(size_t)(b * 1024 + s0 + srow) * 3072 + 2048 + h * 128 + d0 + tx];
  }
  __syncthreads();
#pragma unroll
  for (int j = 0; j < 4; j++){
    int drow = ty + j * 8;
    vt[((size_t)bh * 128 + d0 + drow) * 1024 + s0 + tx] = t[tx][drow];
  }
}

// ---------------- flash attention: per (qtile=128, head, batch) ----------------
__global__ __launch_bounds__(256, 1)
void attn_kernel(const unsigned short* __restrict__ qkv,
                 const unsigned short* __restrict__ vt,
                 unsigned short* __restrict__ ctx)
{
  const int qt = blockIdx.x, h = blockIdx.y, b = blockIdx.z;
  const int tid = threadIdx.x;
  const int w = tid >> 6, lane = tid & 63;
  const int lh = lane & 15, lq = lane >> 4;
  __shared__ unsigned short P[4][32][136];

  const float scale = 0.08838834764831845f;   // 1/sqrt(128)
  const size_t qbase = (size_t)b * 1024 * 3072 + (size_t)h * 128;
  const int q0 = qt * 128 + w * 32;

  frag8 qf[2][4];
#pragma unroll
  for (int r = 0; r < 2; r++)
#pragma unroll
    for (int kk = 0; kk < 4; kk++)
      qf[r][kk] = *(const frag8*)(qkv + qbase + (size_t)(q0 + r * 16 + lh) * 3072 + kk * 32 + lq * 8);

  facc4 O[2][8];
  const facc4 vz = {0.f, 0.f, 0.f, 0.f};
#pragma unroll
  for (int r = 0; r < 2; r++)
#pragma unroll
    for (int c = 0; c < 8; c++) O[r][c] = vz;
  float m[2][4], l[2][4];
#pragma unroll
  for (int r = 0; r < 2; r++)
#pragma unroll
    for (int j = 0; j < 4; j++){ m[r][j] = -3.0e38f; l[r][j] = 0.f; }

  for (int kv0 = 0; kv0 < 1024; kv0 += 128){
    facc4 S[2][8];
#pragma unroll
    for (int r = 0; r < 2; r++)
#pragma unroll
      for (int c = 0; c < 8; c++) S[r][c] = vz;
#pragma unroll
    for (int c = 0; c < 8; c++){
      frag8 kf[4];
#pragma unroll
      for (int kk = 0; kk < 4; kk++)
        kf[kk] = *(const frag8*)(qkv + qbase + 1024 + (size_t)(kv0 + c * 16 + lh) * 3072 + kk * 32 + lq * 8);
#pragma unroll
      for (int kk = 0; kk < 4; kk++)
#pragma unroll
        for (int r = 0; r < 2; r++)
          S[r][c] = MFMA16(qf[r][kk], kf[kk], S[r][c]);
    }
    float tmax[2][4];
#pragma unroll
    for (int r = 0; r < 2; r++)
#pragma unroll
      for (int j = 0; j < 4; j++) tmax[r][j] = -3.0e38f;
#pragma unroll
    for (int r = 0; r < 2; r++)
#pragma unroll
      for (int c = 0; c < 8; c++)
#pragma unroll
        for (int j = 0; j < 4; j++){
          float v = S[r][c][j] * scale;
          S[r][c][j] = v;
          tmax[r][j] = fmaxf(tmax[r][j], v);
        }
#pragma unroll
    for (int mk = 1; mk < 16; mk <<= 1)
#pragma unroll
      for (int r = 0; r < 2; r++)
#pragma unroll
        for (int j = 0; j < 4; j++)
          tmax[r][j] = fmaxf(tmax[r][j], __shfl_xor(tmax[r][j], mk));
    float al[2][4], rs[2][4];
#pragma unroll
    for (int r = 0; r < 2; r++)
#pragma unroll
      for (int j = 0; j < 4; j++){
        float mn = fmaxf(m[r][j], tmax[r][j]);
        al[r][j] = __expf(m[r][j] - mn);
        m[r][j] = mn;
        rs[r][j] = 0.f;
      }
#pragma unroll
    for (int r = 0; r < 2; r++)
#pragma unroll
      for (int c = 0; c < 8; c++)
#pragma unroll
        for (int j = 0; j < 4; j++){
          float p = __expf(S[r][c][j] - m[r][j]);
          S[r][c][j] = p;
          rs[r][j] += p;
        }
#pragma unroll
    for (int mk = 1; mk < 16; mk <<= 1)
#pragma unroll
      for (int r = 0; r < 2; r++)
#pragma unroll
        for (int j = 0; j < 4; j++)
          rs[r][j] += __shfl_xor(rs[r][j], mk);
#pragma unroll
    for (int r = 0; r < 2; r++)
#pragma unroll
      for (int j = 0; j < 4; j++) l[r][j] = l[r][j] * al[r][j] + rs[r][j];
#pragma unroll
    for (int r = 0; r < 2; r++)
#pragma unroll
      for (int c = 0; c < 8; c++)
#pragma unroll
        for (int j = 0; j < 4; j++) O[r][c][j] *= al[r][j];
    // P -> LDS (bf16)
#pragma unroll
    for (int r = 0; r < 2; r++)
#pragma unroll
      for (int c = 0; c < 8; c++)
#pragma unroll
        for (int j = 0; j < 4; j++)
          P[w][r * 16 + lq * 4 + j][c * 16 + lh] = f2bf(S[r][c][j]);
    frag8 pf[2][4];
#pragma unroll
    for (int r = 0; r < 2; r++)
#pragma unroll
      for (int kk = 0; kk < 4; kk++)
        pf[r][kk] = *(const frag8*)&P[w][r * 16 + lh][kk * 32 + lq * 8];
#pragma unroll
    for (int c2 = 0; c2 < 8; c2++){
      frag8 vf[4];
#pragma unroll
      for (int kk = 0; kk < 4; kk++)
        vf[kk] = *(const frag8*)(vt + ((size_t)(b * 8 + h) * 128 + c2 * 16 + lh) * 1024 + kv0 + kk * 32 + lq * 8);
#pragma unroll
      for (int kk = 0; kk < 4; kk++)
#pragma unroll
        for (int r = 0; r < 2; r++)
          O[r][c2] = MFMA16(pf[r][kk], vf[kk], O[r][c2]);
    }
  }
  // epilogue: normalize, stage in LDS, coalesced copy out
#pragma unroll
  for (int r = 0; r < 2; r++)
#pragma unroll
    for (int c2 = 0; c2 < 8; c2++)
#pragma unroll
      for (int j = 0; j < 4; j++)
        P[w][r * 16 + lq * 4 + j][c2 * 16 + lh] = f2bf(O[r][c2][j] / l[r][j]);
  for (int rr = 0; rr < 32; rr++){
    const int token = b * 1024 + qt * 128 + w * 32 + rr;
    const unsigned int val = *(const unsigned int*)&P[w][rr][lane * 2];
    *(unsigned int*)(ctx + (size_t)token * 1024 + h * 128 + lane * 2) = val;
  }
}

// ---------------- EMA smoothing as truncated convolution (q=1-sf, 28 taps) ----------------
__global__ void ema_kernel(const float* __restrict__ both, const float* __restrict__ sfp,
                           float* __restrict__ oact, float* __restrict__ oinst)
{
  const int idx = blockIdx.x * 256 + threadIdx.x;
  if (idx >= 4 * 1024 * 150) return;
  const int c = idx % 150;
  const int bs = idx / 150;
  const int s = bs & 1023;
  float sf = fminf(fmaxf(sfp[0], 0.f), 1.f);
  const float q = 1.f - sf;
  const float* p = both + (size_t)bs * 160 + c;
  float acc = 0.f, wgt = sf;
  const int klim = (s < 28) ? s : 28;
  for (int k = 0; k < klim; k++){ acc += wgt * p[-(long)k * 160]; wgt *= q; }
  if (s <= 28) acc += powf(q, (float)s) * p[-(long)s * 160];
  if (c < 100) oact[(size_t)bs * 100 + c] = acc;
  else         oinst[(size_t)bs * 50 + (c - 100)] = acc;
}

// ---------------- small head kernels ----------------
__global__ void head_c2(const unsigned short* __restrict__ x, const float* __restrict__ wv,
                        const float* __restrict__ bv, float* __restrict__ out)
{
  const int row = blockIdx.x * 4 + (threadIdx.x >> 6);
  const int lane = threadIdx.x & 63;
  float acc = 0.f;
#pragma unroll
  for (int i = 0; i < 8; i++){
    int cidx = i * 64 + lane;
    acc += bf2f(x[(size_t)row * 512 + cidx]) * wv[cidx];
  }
#pragma unroll
  for (int mk = 1; mk < 64; mk <<= 1) acc += __shfl_xor(acc, mk);
  if (lane == 0) out[row] = 1.f / (1.f + __expf(-(acc + bv[0])));
}

__global__ void head_p(const float* __restrict__ x, const float* __restrict__ wv,
                       const float* __restrict__ bv, float* __restrict__ out)
{
  const int row = blockIdx.x * 4 + (threadIdx.x >> 6);
  const int lane = threadIdx.x & 63;
  float acc = 0.f;
#pragma unroll
  for (int i = 0; i < 16; i++){
    int cidx = i * 64 + lane;
    acc += x[(size_t)row * 1024 + cidx] * wv[cidx];
  }
#pragma unroll
  for (int mk = 1; mk < 64; mk <<= 1) acc += __shfl_xor(acc, mk);
  if (lane == 0) out[row] = acc + bv[0];
}

__global__ void pool_softmax(const float* __restrict__ scores, float* __restrict__ poolws,
                             float* __restrict__ outpool)
{
  const int b = blockIdx.x, t = threadIdx.x;
  float4 v = ((const float4*)(scores + (size_t)b * 1024))[t];
  float mx = fmaxf(fmaxf(v.x, v.y), fmaxf(v.z, v.w));
#pragma unroll
  for (int mk = 1; mk < 64; mk <<= 1) mx = fmaxf(mx, __shfl_xor(mx, mk));
  __shared__ float red[8];
  const int w = t >> 6, lane = t & 63;
  if (lane == 0) red[w] = mx;
  __syncthreads();
  mx = fmaxf(fmaxf(red[0], red[1]), fmaxf(red[2], red[3]));
  float4 e;
  e.x = __expf(v.x - mx); e.y = __expf(v.y - mx); e.z = __expf(v.z - mx); e.w = __expf(v.w - mx);
  float sum = e.x + e.y + e.z + e.w;
#pragma unroll
  for (int mk = 1; mk < 64; mk <<= 1) sum += __shfl_xor(sum, mk);
  if (lane == 0) red[4 + w] = sum;
  __syncthreads();
  sum = red[4] + red[5] + red[6] + red[7];
  const float inv = 1.f / sum;
  e.x *= inv; e.y *= inv; e.z *= inv; e.w *= inv;
  ((float4*)(poolws + (size_t)b * 1024))[t] = e;
  ((float4*)(outpool + (size_t)b * 1024))[t] = e;
}

__global__ void globalctx_kernel(const float* __restrict__ pool, const float* __restrict__ ctxf,
                                 float* __restrict__ out)
{
  const int hh = blockIdx.x * 256 + threadIdx.x;
  const int b = blockIdx.y;
  const float* p = pool + (size_t)b * 1024;
  const float* c = ctxf + (size_t)b * 1024 * 1024 + hh;
  float acc = 0.f;
  for (int s = 0; s < 1024; s++) acc += p[s] * c[(size_t)s * 1024];
  out[(size_t)b * 1024 + hh] = acc;
}

// ---------------- launch ----------------
extern "C" void kernel_launch(void* const* d_in, const int* in_sizes, int n_in,
                              void* d_out, int out_size, void* d_ws, size_t ws_size,
                              hipStream_t stream)
{
  if (n_in < 34) return;
  const float* emb     = (const float*)d_in[0];
  const float* W_in    = (const float*)d_in[1];
  const float* b_in    = (const float*)d_in[2];
  const float* ln_in_g = (const float*)d_in[3];
  const float* ln_in_b = (const float*)d_in[4];
  const float* qkv_w   = (const float*)d_in[5];
  const float* qkv_b   = (const float*)d_in[6];
  const float* out_w   = (const float*)d_in[7];
  const float* out_b   = (const float*)d_in[8];
  const float* ff1_w   = (const float*)d_in[9];
  const float* ff1_b   = (const float*)d_in[10];
  const float* ff2_w   = (const float*)d_in[11];
  const float* ff2_b   = (const float*)d_in[12];
  const float* n1_g    = (const float*)d_in[13];
  const float* n1_b    = (const float*)d_in[14];
  const float* n2_g    = (const float*)d_in[15];
  const float* n2_b    = (const float*)d_in[16];
  const float* ln_out_g= (const float*)d_in[17];
  const float* ln_out_b= (const float*)d_in[18];
  const float* a1_w    = (const float*)d_in[19];
  const float* a1_b    = (const float*)d_in[20];
  const float* a2_w    = (const float*)d_in[21];
  const float* a2_b    = (const float*)d_in[22];
  const float* i1_w    = (const float*)d_in[23];
  const float* i1_b    = (const float*)d_in[24];
  const float* i2_w    = (const float*)d_in[25];
  const float* i2_b    = (const float*)d_in[26];
  const float* c1_w    = (const float*)d_in[27];
  const float* c1_b    = (const float*)d_in[28];
  const float* c2_w    = (const float*)d_in[29];
  const float* c2_b    = (const float*)d_in[30];
  const float* p_w     = (const float*)d_in[31];
  const float* p_b     = (const float*)d_in[32];
  const float* sfp     = (const float*)d_in[33];

  char* ws = (char*)d_ws;
  size_t off = 0;
  auto alloc = [&](size_t bytes) -> void* {
    void* p = ws + off;
    off += (bytes + 255) & ~(size_t)255;
    return p;
  };
  unsigned short* emb_bf  = (unsigned short*)alloc((size_t)4096 * 768 * 2);
  unsigned short* Win_bf  = (unsigned short*)alloc((size_t)1024 * 768 * 2);
  unsigned short* qkvw_bf = (unsigned short*)alloc((size_t)3 * 3072 * 1024 * 2);
  unsigned short* outw_bf = (unsigned short*)alloc((size_t)3 * 1024 * 1024 * 2);
  unsigned short* ff1w_bf = (unsigned short*)alloc((size_t)3 * 4096 * 1024 * 2);
  unsigned short* ff2w_bf = (unsigned short*)alloc((size_t)3 * 1024 * 4096 * 2);
  unsigned short* a1w_bf  = (unsigned short*)alloc((size_t)1024 * 1024 * 2);
  unsigned short* a2w_bf  = (unsigned short*)alloc((size_t)128 * 1024 * 2);
  unsigned short* i1w_bf  = (unsigned short*)alloc((size_t)1024 * 1024 * 2);
  unsigned short* i2w_bf  = (unsigned short*)alloc((size_t)128 * 1024 * 2);
  unsigned short* c1w_bf  = (unsigned short*)alloc((size_t)512 * 1024 * 2);
  float* pe      = (float*)alloc((size_t)1024 * 1024 * 4);
  float* t0      = (float*)alloc((size_t)4096 * 1024 * 4);
  float* hres    = (float*)alloc((size_t)4096 * 1024 * 4);
  unsigned short* h_bf = (unsigned short*)alloc((size_t)4096 * 1024 * 2);
  unsigned short* buf1 = (unsigned short*)alloc((size_t)4096 * 4096 * 2); // qkv / ff-activation
  unsigned short* vtb  = (unsigned short*)alloc((size_t)4096 * 1024 * 2); // V^T / head tmp
  unsigned short* ctxb = (unsigned short*)alloc((size_t)4096 * 1024 * 2); // attn out / final ctx bf16
  float* bothb  = (float*)alloc((size_t)4096 * 160 * 4);
  float* scores = (float*)alloc((size_t)4096 * 4);
  float* poolws = (float*)alloc((size_t)4096 * 4);
  if (off > ws_size) return;

  float* out_action = (float*)d_out;
  float* out_instr  = out_action + 4 * 1024 * 100;
  float* out_conf   = out_instr + 4 * 1024 * 50;
  float* out_pool   = out_conf + 4 * 1024;
  float* out_gctx   = out_pool + 4 * 1024;

  // weight/input conversion (single fused launch)
  CvtArgs ca{};
  long blk = 0;
  auto addseg = [&](const float* src, unsigned short* dst, long rows_src, long rows_dst, long Kd){
    CvtSeg& sg = ca.seg[ca.nseg];
    sg.src = src; sg.dst = dst; sg.total = rows_dst * Kd;
    sg.rows_src = (int)rows_src; sg.K = (int)Kd; sg.blk_start = blk;
    blk += (sg.total + 1023) / 1024;
    ca.nseg++;
  };
  addseg(emb,   emb_bf,  4096, 4096, 768);
  addseg(W_in,  Win_bf,  1024, 1024, 768);
  addseg(qkv_w, qkvw_bf, 9216, 9216, 1024);
  addseg(out_w, outw_bf, 3072, 3072, 1024);
  addseg(ff1_w, ff1w_bf, 12288, 12288, 1024);
  addseg(ff2_w, ff2w_bf, 3072, 3072, 4096);
  addseg(a1_w,  a1w_bf,  1024, 1024, 1024);
  addseg(a2_w,  a2w_bf,  100,  128,  1024);
  addseg(i1_w,  i1w_bf,  1024, 1024, 1024);
  addseg(i2_w,  i2w_bf,  50,   128,  1024);
  addseg(c1_w,  c1w_bf,  512,  512,  1024);
  convert_all<<<dim3((unsigned)blk), dim3(256), 0, stream>>>(ca);

  pe_kernel<<<dim3(1024), dim3(256), 0, stream>>>(pe);

  // input projection + (pos enc + LN)
  gemm_bt<0><<<dim3(32, 8), dim3(256), 0, stream>>>(emb_bf, Win_bf, b_in, t0, 768, 1024, 0, 1024);
  ln_kernel<<<dim3(4096), dim3(256), 0, stream>>>(t0, pe, 2, ln_in_g, ln_in_b, hres, h_bf);

  for (int l = 0; l < 3; l++){
    gemm_bt<1><<<dim3(32, 24), dim3(256), 0, stream>>>(h_bf, qkvw_bf + (size_t)l * 3072 * 1024,
                                                       qkv_b + (size_t)l * 3072, buf1, 1024, 3072, 0, 3072);
    transpose_v<<<dim3(32, 4, 32), dim3(32, 8), 0, stream>>>(buf1, vtb);
    attn_kernel<<<dim3(8, 8, 4), dim3(256), 0, stream>>>(buf1, vtb, ctxb);
    gemm_bt<0><<<dim3(32, 8), dim3(256), 0, stream>>>(ctxb, outw_bf + (size_t)l * 1024 * 1024,
                                                      out_b + (size_t)l * 1024, t0, 1024, 1024, 0, 1024);
    ln_kernel<<<dim3(4096), dim3(256), 0, stream>>>(hres, t0, 1, n1_g + l * 1024, n1_b + l * 1024, hres, h_bf);
    gemm_bt<2><<<dim3(32, 32), dim3(256), 0, stream>>>(h_bf, ff1w_bf + (size_t)l * 4096 * 1024,
                                                       ff1_b + (size_t)l * 4096, buf1, 1024, 4096, 0, 4096);
    gemm_bt<0><<<dim3(32, 8), dim3(256), 0, stream>>>(buf1, ff2w_bf + (size_t)l * 1024 * 4096,
                                                      ff2_b + (size_t)l * 1024, t0, 4096, 1024, 0, 1024);
    ln_kernel<<<dim3(4096), dim3(256), 0, stream>>>(hres, t0, 1, n2_g + l * 1024, n2_b + l * 1024, hres, h_bf);
  }

  // final LN -> ctx (f32 in t0, bf16 in ctxb)
  ln_kernel<<<dim3(4096), dim3(256), 0, stream>>>(hres, nullptr, 0, ln_out_g, ln_out_b, t0, ctxb);

  // heads
  gemm_bt<2><<<dim3(32, 8), dim3(256), 0, stream>>>(ctxb, a1w_bf, a1_b, vtb, 1024, 1024, 0, 1024);
  gemm_bt<0><<<dim3(32, 1), dim3(256), 0, stream>>>(vtb, a2w_bf, a2_b, bothb, 1024, 160, 0, 100);
  gemm_bt<2><<<dim3(32, 8), dim3(256), 0, stream>>>(ctxb, i1w_bf, i1_b, vtb, 1024, 1024, 0, 1024);
  gemm_bt<0><<<dim3(32, 1), dim3(256), 0, stream>>>(vtb, i2w_bf, i2_b, bothb, 1024, 160, 100, 50);
  gemm_bt<2><<<dim3(32, 4), dim3(256), 0, stream>>>(ctxb, c1w_bf, c1_b, vtb, 1024, 512, 0, 512);
  head_c2<<<dim3(1024), dim3(256), 0, stream>>>(vtb, c2_w, c2_b, out_conf);
  head_p<<<dim3(1024), dim3(256), 0, stream>>>(t0, p_w, p_b, scores);
  pool_softmax<<<dim3(4), dim3(256), 0, stream>>>(scores, poolws, out_pool);
  globalctx_kernel<<<dim3(4, 4), dim3(256), 0, stream>>>(poolws, t0, out_gctx);
  ema_kernel<<<dim3(2400), dim3(256), 0, stream>>>(bothb, sfp, out_action, out_instr);
}

// Round 3
// 1068.976 us; speedup vs baseline: 1.0886x; 1.0886x over previous
//
#include <hip/hip_runtime.h>

// ---------------- types & helpers ----------------
typedef __attribute__((ext_vector_type(8))) short frag8;   // 8 x bf16 (4 VGPRs)
typedef __attribute__((ext_vector_type(4))) float facc4;   // 4 x f32 accum

#define MFMA16(a,b,c) __builtin_amdgcn_mfma_f32_16x16x32_bf16((a),(b),(c),0,0,0)

__device__ __forceinline__ unsigned short f2bf(float f){
  unsigned int u = __builtin_bit_cast(unsigned int, f);
  u += 0x7FFFu + ((u >> 16) & 1u);           // RNE
  return (unsigned short)(u >> 16);
}
__device__ __forceinline__ float bf2f(unsigned short h){
  unsigned int u = ((unsigned int)h) << 16;
  return __builtin_bit_cast(float, u);
}
__device__ __forceinline__ float gelu_f(float x){
  return 0.5f * x * (1.0f + erff(x * 0.70710678118654752440f));
}
__device__ __forceinline__ void gload16(const void* g, void* l){
  __builtin_amdgcn_global_load_lds(
      (const __attribute__((address_space(1))) void*)g,
      (__attribute__((address_space(3))) void*)l, 16, 0, 0);
}

// ---------------- fused f32->bf16 weight conversion (with row padding) ----------------
struct CvtSeg { const float* src; unsigned short* dst; long total; long blk_start; int rows_src; int K; };
struct CvtArgs { CvtSeg seg[12]; int nseg; };

__global__ void convert_all(CvtArgs a){
  long blk = blockIdx.x;
  int si = 0;
  for (int i = 1; i < a.nseg; i++) if (blk >= a.seg[i].blk_start) si = i;
  CvtSeg s = a.seg[si];
  long i = ((blk - s.blk_start) * 256 + threadIdx.x) * 4L;
  if (i >= s.total) return;
  long row = i / s.K;
  ushort4 o;
  if (row < s.rows_src){
    float4 v = *(const float4*)(s.src + i);
    o.x = f2bf(v.x); o.y = f2bf(v.y); o.z = f2bf(v.z); o.w = f2bf(v.w);
  } else { o.x = 0; o.y = 0; o.z = 0; o.w = 0; }
  *(ushort4*)(s.dst + i) = o;
}

// ---------------- positional encoding table ----------------
__global__ void pe_kernel(float* __restrict__ pe){
  const int s = blockIdx.x;
  const int t = threadIdx.x;
  float4 o;
#pragma unroll
  for (int e = 0; e < 4; e++){
    int c = t * 4 + e;
    int i2 = c & ~1;   // 2i
    float dv = expf(-0.0089944730195080f * (float)i2); // log(10000)/1024
    float ang = (float)s * dv;
    ((float*)&o)[e] = (c & 1) ? cosf(ang) : sinf(ang);
  }
  *(float4*)(pe + (size_t)s * 1024 + t * 4) = o;
}

// ---------------- GEMM: C[M,N] = A[M,K] * W[N,K]^T + bias ----------------
// EPI: 0 = f32 out, 1 = bf16 out, 2 = gelu -> bf16 out
template<int EPI>
__global__ __launch_bounds__(256, 2)
void gemm_bt(const unsigned short* __restrict__ A,
             const unsigned short* __restrict__ W,
             const float* __restrict__ bias,
             void* __restrict__ Cout,
             int K, int ldC, int coloff, int nvalid)
{
  __shared__ unsigned short As[128 * 32];
  __shared__ unsigned short Bs[128 * 32];
  const int tid = threadIdx.x;
  const int w = tid >> 6, lane = tid & 63;
  const int lh = lane & 15, lq = lane >> 4;
  const int wr = w >> 1, wc = w & 1;
  const long row0 = (long)blockIdx.x * 128;
  const long col0 = (long)blockIdx.y * 128;

  facc4 acc[4][4];
  const facc4 vz = {0.f, 0.f, 0.f, 0.f};
#pragma unroll
  for (int r = 0; r < 4; r++)
#pragma unroll
    for (int c = 0; c < 4; c++) acc[r][c] = vz;

  const int arow = w * 16 + (lane >> 2);
  const int aseg = (lane & 3) * 8;
  const unsigned short* A0 = A + (row0 + arow) * (long)K + aseg;
  const unsigned short* A1 = A + (row0 + 64 + arow) * (long)K + aseg;
  const unsigned short* W0 = W + (col0 + arow) * (long)K + aseg;
  const unsigned short* W1 = W + (col0 + 64 + arow) * (long)K + aseg;
  char* lA0 = (char*)As + w * 1024;
  char* lA1 = (char*)As + 4096 + w * 1024;
  char* lB0 = (char*)Bs + w * 1024;
  char* lB1 = (char*)Bs + 4096 + w * 1024;

  for (int k0 = 0; k0 < K; k0 += 32){
    gload16(A0 + k0, lA0);
    gload16(A1 + k0, lA1);
    gload16(W0 + k0, lB0);
    gload16(W1 + k0, lB1);
    __syncthreads();
    frag8 af[4], bf[4];
#pragma unroll
    for (int r = 0; r < 4; r++) af[r] = *(const frag8*)&As[(wr * 64 + r * 16 + lh) * 32 + lq * 8];
#pragma unroll
    for (int c = 0; c < 4; c++) bf[c] = *(const frag8*)&Bs[(wc * 64 + c * 16 + lh) * 32 + lq * 8];
#pragma unroll
    for (int r = 0; r < 4; r++)
#pragma unroll
      for (int c = 0; c < 4; c++)
        acc[r][c] = MFMA16(af[r], bf[c], acc[r][c]);
    __syncthreads();
  }

#pragma unroll
  for (int c = 0; c < 4; c++){
    const int colt = wc * 64 + c * 16 + lh;
    const long gcol = col0 + colt;
    const bool ok = gcol < nvalid;
    const float bv = ok ? bias[gcol] : 0.f;
#pragma unroll
    for (int r = 0; r < 4; r++){
#pragma unroll
      for (int j = 0; j < 4; j++){
        if (!ok) continue;
        const long grow = row0 + wr * 64 + r * 16 + lq * 4 + j;
        float v = acc[r][c][j] + bv;
        if (EPI == 2) v = gelu_f(v);
        const long off = grow * (long)ldC + coloff + gcol;
        if (EPI == 0) ((float*)Cout)[off] = v;
        else          ((unsigned short*)Cout)[off] = f2bf(v);
      }
    }
  }
}

// ---------------- LayerNorm (row=1024), residual in f32, bf16 copy out ----------------
// bmode: 0 = none, 1 = add bsrc[row], 2 = add bsrc[row & 1023]  (pos enc)
__global__ __launch_bounds__(256)
void ln_kernel(const float* __restrict__ a, const float* __restrict__ bsrc, int bmode,
               const float* __restrict__ g, const float* __restrict__ be,
               float* __restrict__ of32, unsigned short* __restrict__ obf)
{
  const int row = blockIdx.x;
  const int t = threadIdx.x;
  float4 x = ((const float4*)(a + (size_t)row * 1024))[t];
  if (bmode){
    const size_t brow = (bmode == 1) ? (size_t)row : (size_t)(row & 1023);
    float4 y = ((const float4*)(bsrc + brow * 1024))[t];
    x.x += y.x; x.y += y.y; x.z += y.z; x.w += y.w;
  }
  float s = x.x + x.y + x.z + x.w;
  float ss = x.x * x.x + x.y * x.y + x.z * x.z + x.w * x.w;
#pragma unroll
  for (int mk = 1; mk < 64; mk <<= 1){ s += __shfl_xor(s, mk); ss += __shfl_xor(ss, mk); }
  __shared__ float red[8];
  const int w = t >> 6, lane = t & 63;
  if (lane == 0){ red[w] = s; red[4 + w] = ss; }
  __syncthreads();
  s = red[0] + red[1] + red[2] + red[3];
  ss = red[4] + red[5] + red[6] + red[7];
  const float mean = s * (1.f / 1024.f);
  const float var = ss * (1.f / 1024.f) - mean * mean;
  const float rstd = rsqrtf(var + 1e-5f);
  float4 gg = ((const float4*)g)[t];
  float4 bb = ((const float4*)be)[t];
  float4 o;
  o.x = (x.x - mean) * rstd * gg.x + bb.x;
  o.y = (x.y - mean) * rstd * gg.y + bb.y;
  o.z = (x.z - mean) * rstd * gg.z + bb.z;
  o.w = (x.w - mean) * rstd * gg.w + bb.w;
  if (of32) ((float4*)(of32 + (size_t)row * 1024))[t] = o;
  if (obf){
    ushort4 hh;
    hh.x = f2bf(o.x); hh.y = f2bf(o.y); hh.z = f2bf(o.z); hh.w = f2bf(o.w);
    ((ushort4*)(obf + (size_t)row * 1024))[t] = hh;
  }
}

// ---------------- V transpose: vt[b][h][d][s] ----------------
__global__ void transpose_v(const unsigned short* __restrict__ qkv, unsigned short* __restrict__ vt){
  __shared__ unsigned short t[32][33];
  const int s0 = blockIdx.x * 32;
  const int d0 = blockIdx.y * 32;
  const int bh = blockIdx.z;
  const int b = bh >> 3, h = bh & 7;
  const int tx = threadIdx.x, ty = threadIdx.y;
#pragma unroll
  for (int j = 0; j < 4; j++){
    int srow = ty + j * 8;
    t[srow][tx] = qkv[(size_t)(b * 1024 + s0 + srow) * 3072 + 2048 + h * 128 + d0 + tx];
  }
  __syncthreads();
#pragma unroll
  for (int j = 0; j < 4; j++){
    int drow = ty + j * 8;
    vt[((size_t)bh * 128 + d0 + drow) * 1024 + s0 + tx] = t[tx][drow];
  }
}

// ---------------- flash attention v2: qtile=64, KV staged in LDS (dbuf + swizzle) ----------------
// grid (16, 8, 4) = (qt, h, b); 256 threads, wave w owns q rows qt*64 + w*16.
__global__ __launch_bounds__(256, 2)
void attn_kernel(const unsigned short* __restrict__ qkv,
                 const unsigned short* __restrict__ vt,
                 unsigned short* __restrict__ ctx)
{
  const int qt = blockIdx.x, h = blockIdx.y, b = blockIdx.z;
  const int tid = threadIdx.x;
  const int w = tid >> 6, lane = tid & 63;
  const int lh = lane & 15, lq = lane >> 4;

  __shared__ unsigned short Ks[2][64 * 128];   // [kv][d], swizzled, 2x16KB
  __shared__ unsigned short Vs[2][128 * 64];   // [d][kv], swizzled, 2x16KB
  __shared__ unsigned short P[4][16][72];      // per-wave P tile, padded

  const float scale = 0.08838834764831845f;    // 1/sqrt(128)
  const int q0 = qt * 64 + w * 16;

  // Q fragments (16 q-rows per wave)
  frag8 qf[4];
#pragma unroll
  for (int kk = 0; kk < 4; kk++)
    qf[kk] = *(const frag8*)(qkv + ((size_t)(b * 1024 + q0 + lh)) * 3072 + h * 128 + kk * 32 + lq * 8);

  const unsigned short* Kg = qkv + (size_t)b * 1024 * 3072 + 1024 + h * 128; // + kv*3072
  const unsigned short* Vg = vt + (size_t)(b * 8 + h) * 128 * 1024;          // + d*1024 + kv

  // staging: K tile 64x128 (256B rows, 16 chunks), V tile 128x64 (128B rows, 8 chunks)
  // LDS dest is linear (HW: wave base + lane*16); swizzle applied by pre-swizzling the
  // per-lane GLOBAL source chunk, read side XORs the same ((row&7)<<4). (rule 21)
  const int k_rsub = lane >> 4;     // K row within 4-row group
  const int k_c    = lane & 15;     // K chunk idx
  const int v_rsub = lane >> 3;     // V row within 8-row group
  const int v_c    = lane & 7;      // V chunk idx

  auto stage = [&](int buf, int kv0){
#pragma unroll
    for (int i = 0; i < 4; i++){
      const int seg = i * 4 + w;                  // 0..15 (1KB segments)
      const int kr = seg * 4 + k_rsub;            // 0..63
      const int ksc = k_c ^ (kr & 7);
      gload16(Kg + (size_t)(kv0 + kr) * 3072 + ksc * 8,
              (char*)Ks + buf * 16384 + seg * 1024);
      const int vr = seg * 8 + v_rsub;            // 0..127
      const int vsc = v_c ^ (vr & 7);
      gload16(Vg + (size_t)vr * 1024 + kv0 + vsc * 8,
              (char*)Vs + buf * 16384 + seg * 1024);
    }
  };

  facc4 O[8];
  const facc4 vz = {0.f, 0.f, 0.f, 0.f};
#pragma unroll
  for (int c = 0; c < 8; c++) O[c] = vz;
  float m[4], l[4];
#pragma unroll
  for (int j = 0; j < 4; j++){ m[j] = -3.0e38f; l[j] = 0.f; }

  stage(0, 0);
  __syncthreads();

  for (int t = 0; t < 16; t++){
    const int cur = t & 1;
    if (t < 15) stage(cur ^ 1, (t + 1) * 64);    // async prefetch into other buffer

    // ---- QK^T : S[16q x 64kv] ----
    facc4 S[4];
#pragma unroll
    for (int c = 0; c < 4; c++) S[c] = vz;
    const char* Kb = (const char*)Ks + cur * 16384;
#pragma unroll
    for (int c = 0; c < 4; c++){
      const int row = c * 16 + lh;
#pragma unroll
      for (int kk = 0; kk < 4; kk++){
        frag8 kf = *(const frag8*)(Kb + row * 256 + ((kk * 64 + lq * 16) ^ ((row & 7) << 4)));
        S[c] = MFMA16(qf[kk], kf, S[c]);
      }
    }
    // ---- online softmax (rows = lq*4+j) ----
    float tmax[4] = {-3.0e38f, -3.0e38f, -3.0e38f, -3.0e38f};
#pragma unroll
    for (int c = 0; c < 4; c++)
#pragma unroll
      for (int j = 0; j < 4; j++){
        float v = S[c][j] * scale;
        S[c][j] = v;
        tmax[j] = fmaxf(tmax[j], v);
      }
#pragma unroll
    for (int mk = 1; mk < 16; mk <<= 1)
#pragma unroll
      for (int j = 0; j < 4; j++) tmax[j] = fmaxf(tmax[j], __shfl_xor(tmax[j], mk));
    float al[4], rs[4];
#pragma unroll
    for (int j = 0; j < 4; j++){
      float mn = fmaxf(m[j], tmax[j]);
      al[j] = __expf(m[j] - mn);
      m[j] = mn;
      rs[j] = 0.f;
    }
#pragma unroll
    for (int c = 0; c < 4; c++)
#pragma unroll
      for (int j = 0; j < 4; j++){
        float p = __expf(S[c][j] - m[j]);
        S[c][j] = p;
        rs[j] += p;
      }
#pragma unroll
    for (int mk = 1; mk < 16; mk <<= 1)
#pragma unroll
      for (int j = 0; j < 4; j++) rs[j] += __shfl_xor(rs[j], mk);
#pragma unroll
    for (int j = 0; j < 4; j++) l[j] = l[j] * al[j] + rs[j];
#pragma unroll
    for (int c = 0; c < 8; c++)
#pragma unroll
      for (int j = 0; j < 4; j++) O[c][j] *= al[j];

    // ---- P -> LDS (bf16), re-read as A fragments ----
#pragma unroll
    for (int c = 0; c < 4; c++)
#pragma unroll
      for (int j = 0; j < 4; j++)
        P[w][lq * 4 + j][c * 16 + lh] = f2bf(S[c][j]);
    frag8 pf[2];
#pragma unroll
    for (int kk = 0; kk < 2; kk++)
      pf[kk] = *(const frag8*)&P[w][lh][kk * 32 + lq * 8];

    // ---- PV : O += P[16x64] * V[64x128] ----
    const char* Vb = (const char*)Vs + cur * 16384;
#pragma unroll
    for (int c2 = 0; c2 < 8; c2++){
      const int row = c2 * 16 + lh;
#pragma unroll
      for (int kk = 0; kk < 2; kk++){
        frag8 vf = *(const frag8*)(Vb + row * 128 + ((kk * 64 + lq * 16) ^ ((row & 7) << 4)));
        O[c2] = MFMA16(pf[kk], vf, O[c2]);
      }
    }
    __syncthreads();   // drains prefetch vmcnt + guards LDS buffer swap
  }

  // ---- epilogue: normalize, stage through (dead) Ks for coalesced 256B stores ----
  unsigned short* Es = (unsigned short*)Ks;    // [4][16][128]
#pragma unroll
  for (int c2 = 0; c2 < 8; c2++)
#pragma unroll
    for (int j = 0; j < 4; j++)
      Es[w * 2048 + (lq * 4 + j) * 128 + c2 * 16 + lh] = f2bf(O[c2][j] / l[j]);
  __syncthreads();
  const int token0 = b * 1024 + qt * 64 + w * 16;
#pragma unroll
  for (int rr = 0; rr < 16; rr++){
    const unsigned int val = *(const unsigned int*)&Es[w * 2048 + rr * 128 + lane * 2];
    *(unsigned int*)(ctx + (size_t)(token0 + rr) * 1024 + h * 128 + lane * 2) = val;
  }
}

// ---------------- EMA smoothing as truncated convolution (q=1-sf, 28 taps) ----------------
__global__ void ema_kernel(const float* __restrict__ both, const float* __restrict__ sfp,
                           float* __restrict__ oact, float* __restrict__ oinst)
{
  const int idx = blockIdx.x * 256 + threadIdx.x;
  if (idx >= 4 * 1024 * 150) return;
  const int c = idx % 150;
  const int bs = idx / 150;
  const int s = bs & 1023;
  float sf = fminf(fmaxf(sfp[0], 0.f), 1.f);
  const float q = 1.f - sf;
  const float* p = both + (size_t)bs * 160 + c;
  float acc = 0.f, wgt = sf;
  const int klim = (s < 28) ? s : 28;
  for (int k = 0; k < klim; k++){ acc += wgt * p[-(long)k * 160]; wgt *= q; }
  if (s <= 28) acc += powf(q, (float)s) * p[-(long)s * 160];
  if (c < 100) oact[(size_t)bs * 100 + c] = acc;
  else         oinst[(size_t)bs * 50 + (c - 100)] = acc;
}

// ---------------- small head kernels ----------------
__global__ void head_c2(const unsigned short* __restrict__ x, const float* __restrict__ wv,
                        const float* __restrict__ bv, float* __restrict__ out)
{
  const int row = blockIdx.x * 4 + (threadIdx.x >> 6);
  const int lane = threadIdx.x & 63;
  float acc = 0.f;
#pragma unroll
  for (int i = 0; i < 8; i++){
    int cidx = i * 64 + lane;
    acc += bf2f(x[(size_t)row * 512 + cidx]) * wv[cidx];
  }
#pragma unroll
  for (int mk = 1; mk < 64; mk <<= 1) acc += __shfl_xor(acc, mk);
  if (lane == 0) out[row] = 1.f / (1.f + __expf(-(acc + bv[0])));
}

__global__ void head_p(const float* __restrict__ x, const float* __restrict__ wv,
                       const float* __restrict__ bv, float* __restrict__ out)
{
  const int row = blockIdx.x * 4 + (threadIdx.x >> 6);
  const int lane = threadIdx.x & 63;
  float acc = 0.f;
#pragma unroll
  for (int i = 0; i < 16; i++){
    int cidx = i * 64 + lane;
    acc += x[(size_t)row * 1024 + cidx] * wv[cidx];
  }
#pragma unroll
  for (int mk = 1; mk < 64; mk <<= 1) acc += __shfl_xor(acc, mk);
  if (lane == 0) out[row] = acc + bv[0];
}

__global__ void pool_softmax(const float* __restrict__ scores, float* __restrict__ poolws,
                             float* __restrict__ outpool)
{
  const int b = blockIdx.x, t = threadIdx.x;
  float4 v = ((const float4*)(scores + (size_t)b * 1024))[t];
  float mx = fmaxf(fmaxf(v.x, v.y), fmaxf(v.z, v.w));
#pragma unroll
  for (int mk = 1; mk < 64; mk <<= 1) mx = fmaxf(mx, __shfl_xor(mx, mk));
  __shared__ float red[8];
  const int w = t >> 6, lane = t & 63;
  if (lane == 0) red[w] = mx;
  __syncthreads();
  mx = fmaxf(fmaxf(red[0], red[1]), fmaxf(red[2], red[3]));
  float4 e;
  e.x = __expf(v.x - mx); e.y = __expf(v.y - mx); e.z = __expf(v.z - mx); e.w = __expf(v.w - mx);
  float sum = e.x + e.y + e.z + e.w;
#pragma unroll
  for (int mk = 1; mk < 64; mk <<= 1) sum += __shfl_xor(sum, mk);
  if (lane == 0) red[4 + w] = sum;
  __syncthreads();
  sum = red[4] + red[5] + red[6] + red[7];
  const float inv = 1.f / sum;
  e.x *= inv; e.y *= inv; e.z *= inv; e.w *= inv;
  ((float4*)(poolws + (size_t)b * 1024))[t] = e;
  ((float4*)(outpool + (size_t)b * 1024))[t] = e;
}

__global__ void globalctx_kernel(const float* __restrict__ pool, const float* __restrict__ ctxf,
                                 float* __restrict__ out)
{
  const int hh = blockIdx.x * 256 + threadIdx.x;
  const int b = blockIdx.y;
  const float* p = pool + (size_t)b * 1024;
  const float* c = ctxf + (size_t)b * 1024 * 1024 + hh;
  float acc = 0.f;
  for (int s = 0; s < 1024; s++) acc += p[s] * c[(size_t)s * 1024];
  out[(size_t)b * 1024 + hh] = acc;
}

// ---------------- launch ----------------
extern "C" void kernel_launch(void* const* d_in, const int* in_sizes, int n_in,
                              void* d_out, int out_size, void* d_ws, size_t ws_size,
                              hipStream_t stream)
{
  if (n_in < 34) return;
  const float* emb     = (const float*)d_in[0];
  const float* W_in    = (const float*)d_in[1];
  const float* b_in    = (const float*)d_in[2];
  const float* ln_in_g = (const float*)d_in[3];
  const float* ln_in_b = (const float*)d_in[4];
  const float* qkv_w   = (const float*)d_in[5];
  const float* qkv_b   = (const float*)d_in[6];
  const float* out_w   = (const float*)d_in[7];
  const float* out_b   = (const float*)d_in[8];
  const float* ff1_w   = (const float*)d_in[9];
  const float* ff1_b   = (const float*)d_in[10];
  const float* ff2_w   = (const float*)d_in[11];
  const float* ff2_b   = (const float*)d_in[12];
  const float* n1_g    = (const float*)d_in[13];
  const float* n1_b    = (const float*)d_in[14];
  const float* n2_g    = (const float*)d_in[15];
  const float* n2_b    = (const float*)d_in[16];
  const float* ln_out_g= (const float*)d_in[17];
  const float* ln_out_b= (const float*)d_in[18];
  const float* a1_w    = (const float*)d_in[19];
  const float* a1_b    = (const float*)d_in[20];
  const float* a2_w    = (const float*)d_in[21];
  const float* a2_b    = (const float*)d_in[22];
  const float* i1_w    = (const float*)d_in[23];
  const float* i1_b    = (const float*)d_in[24];
  const float* i2_w    = (const float*)d_in[25];
  const float* i2_b    = (const float*)d_in[26];
  const float* c1_w    = (const float*)d_in[27];
  const float* c1_b    = (const float*)d_in[28];
  const float* c2_w    = (const float*)d_in[29];
  const float* c2_b    = (const float*)d_in[30];
  const float* p_w     = (const float*)d_in[31];
  const float* p_b     = (const float*)d_in[32];
  const float* sfp     = (const float*)d_in[33];

  char* ws = (char*)d_ws;
  size_t off = 0;
  auto alloc = [&](size_t bytes) -> void* {
    void* p = ws + off;
    off += (bytes + 255) & ~(size_t)255;
    return p;
  };
  unsigned short* emb_bf  = (unsigned short*)alloc((size_t)4096 * 768 * 2);
  unsigned short* Win_bf  = (unsigned short*)alloc((size_t)1024 * 768 * 2);
  unsigned short* qkvw_bf = (unsigned short*)alloc((size_t)3 * 3072 * 1024 * 2);
  unsigned short* outw_bf = (unsigned short*)alloc((size_t)3 * 1024 * 1024 * 2);
  unsigned short* ff1w_bf = (unsigned short*)alloc((size_t)3 * 4096 * 1024 * 2);
  unsigned short* ff2w_bf = (unsigned short*)alloc((size_t)3 * 1024 * 4096 * 2);
  unsigned short* a1w_bf  = (unsigned short*)alloc((size_t)1024 * 1024 * 2);
  unsigned short* a2w_bf  = (unsigned short*)alloc((size_t)128 * 1024 * 2);
  unsigned short* i1w_bf  = (unsigned short*)alloc((size_t)1024 * 1024 * 2);
  unsigned short* i2w_bf  = (unsigned short*)alloc((size_t)128 * 1024 * 2);
  unsigned short* c1w_bf  = (unsigned short*)alloc((size_t)512 * 1024 * 2);
  float* pe      = (float*)alloc((size_t)1024 * 1024 * 4);
  float* t0      = (float*)alloc((size_t)4096 * 1024 * 4);
  float* hres    = (float*)alloc((size_t)4096 * 1024 * 4);
  unsigned short* h_bf = (unsigned short*)alloc((size_t)4096 * 1024 * 2);
  unsigned short* buf1 = (unsigned short*)alloc((size_t)4096 * 4096 * 2); // qkv / ff-activation
  unsigned short* vtb  = (unsigned short*)alloc((size_t)4096 * 1024 * 2); // V^T / head tmp
  unsigned short* ctxb = (unsigned short*)alloc((size_t)4096 * 1024 * 2); // attn out / final ctx bf16
  float* bothb  = (float*)alloc((size_t)4096 * 160 * 4);
  float* scores = (float*)alloc((size_t)4096 * 4);
  float* poolws = (float*)alloc((size_t)4096 * 4);
  if (off > ws_size) return;

  float* out_action = (float*)d_out;
  float* out_instr  = out_action + 4 * 1024 * 100;
  float* out_conf   = out_instr + 4 * 1024 * 50;
  float* out_pool   = out_conf + 4 * 1024;
  float* out_gctx   = out_pool + 4 * 1024;

  // weight/input conversion (single fused launch)
  CvtArgs ca{};
  long blk = 0;
  auto addseg = [&](const float* src, unsigned short* dst, long rows_src, long rows_dst, long Kd){
    CvtSeg& sg = ca.seg[ca.nseg];
    sg.src = src; sg.dst = dst; sg.total = rows_dst * Kd;
    sg.rows_src = (int)rows_src; sg.K = (int)Kd; sg.blk_start = blk;
    blk += (sg.total + 1023) / 1024;
    ca.nseg++;
  };
  addseg(emb,   emb_bf,  4096, 4096, 768);
  addseg(W_in,  Win_bf,  1024, 1024, 768);
  addseg(qkv_w, qkvw_bf, 9216, 9216, 1024);
  addseg(out_w, outw_bf, 3072, 3072, 1024);
  addseg(ff1_w, ff1w_bf, 12288, 12288, 1024);
  addseg(ff2_w, ff2w_bf, 3072, 3072, 4096);
  addseg(a1_w,  a1w_bf,  1024, 1024, 1024);
  addseg(a2_w,  a2w_bf,  100,  128,  1024);
  addseg(i1_w,  i1w_bf,  1024, 1024, 1024);
  addseg(i2_w,  i2w_bf,  50,   128,  1024);
  addseg(c1_w,  c1w_bf,  512,  512,  1024);
  convert_all<<<dim3((unsigned)blk), dim3(256), 0, stream>>>(ca);

  pe_kernel<<<dim3(1024), dim3(256), 0, stream>>>(pe);

  // input projection + (pos enc + LN)
  gemm_bt<0><<<dim3(32, 8), dim3(256), 0, stream>>>(emb_bf, Win_bf, b_in, t0, 768, 1024, 0, 1024);
  ln_kernel<<<dim3(4096), dim3(256), 0, stream>>>(t0, pe, 2, ln_in_g, ln_in_b, hres, h_bf);

  for (int l = 0; l < 3; l++){
    gemm_bt<1><<<dim3(32, 24), dim3(256), 0, stream>>>(h_bf, qkvw_bf + (size_t)l * 3072 * 1024,
                                                       qkv_b + (size_t)l * 3072, buf1, 1024, 3072, 0, 3072);
    transpose_v<<<dim3(32, 4, 32), dim3(32, 8), 0, stream>>>(buf1, vtb);
    attn_kernel<<<dim3(16, 8, 4), dim3(256), 0, stream>>>(buf1, vtb, ctxb);
    gemm_bt<0><<<dim3(32, 8), dim3(256), 0, stream>>>(ctxb, outw_bf + (size_t)l * 1024 * 1024,
                                                      out_b + (size_t)l * 1024, t0, 1024, 1024, 0, 1024);
    ln_kernel<<<dim3(4096), dim3(256), 0, stream>>>(hres, t0, 1, n1_g + l * 1024, n1_b + l * 1024, hres, h_bf);
    gemm_bt<2><<<dim3(32, 32), dim3(256), 0, stream>>>(h_bf, ff1w_bf + (size_t)l * 4096 * 1024,
                                                       ff1_b + (size_t)l * 4096, buf1, 1024, 4096, 0, 4096);
    gemm_bt<0><<<dim3(32, 8), dim3(256), 0, stream>>>(buf1, ff2w_bf + (size_t)l * 1024 * 4096,
                                                      ff2_b + (size_t)l * 1024, t0, 4096, 1024, 0, 1024);
    ln_kernel<<<dim3(4096), dim3(256), 0, stream>>>(hres, t0, 1, n2_g + l * 1024, n2_b + l * 1024, hres, h_bf);
  }

  // final LN -> ctx (f32 in t0, bf16 in ctxb)
  ln_kernel<<<dim3(4096), dim3(256), 0, stream>>>(hres, nullptr, 0, ln_out_g, ln_out_b, t0, ctxb);

  // heads
  gemm_bt<2><<<dim3(32, 8), dim3(256), 0, stream>>>(ctxb, a1w_bf, a1_b, vtb, 1024, 1024, 0, 1024);
  gemm_bt<0><<<dim3(32, 1), dim3(256), 0, stream>>>(vtb, a2w_bf, a2_b, bothb, 1024, 160, 0, 100);
  gemm_bt<2><<<dim3(32, 8), dim3(256), 0, stream>>>(ctxb, i1w_bf, i1_b, vtb, 1024, 1024, 0, 1024);
  gemm_bt<0><<<dim3(32, 1), dim3(256), 0, stream>>>(vtb, i2w_bf, i2_b, bothb, 1024, 160, 100, 50);
  gemm_bt<2><<<dim3(32, 4), dim3(256), 0, stream>>>(ctxb, c1w_bf, c1_b, vtb, 1024, 512, 0, 512);
  head_c2<<<dim3(1024), dim3(256), 0, stream>>>(vtb, c2_w, c2_b, out_conf);
  head_p<<<dim3(1024), dim3(256), 0, stream>>>(t0, p_w, p_b, scores);
  pool_softmax<<<dim3(4), dim3(256), 0, stream>>>(scores, poolws, out_pool);
  globalctx_kernel<<<dim3(4, 4), dim3(256), 0, stream>>>(poolws, t0, out_gctx);
  ema_kernel<<<dim3(2400), dim3(256), 0, stream>>>(bothb, sfp, out_action, out_instr);
}